// Round 14
// baseline (19010.339 us; speedup 1.0000x reference)
//
#include <hip/hip_runtime.h>
#include <math.h>
#include <cmath>

struct AnchorArgF { float a[9][4]; };

// ---------------- K1: conv 3x3, 512->512, pad 1; fp32, BLAS kc=384 blocking (BIT-EXACT chain):
// flat k=(ci,kh,kw) ascending; per-output fma chain per 384-block, rounded fold-adds.
// v5: uniform-branch fold split — fast body (no guards) for the 500/512 kk with no fold. ----------------
__global__ __launch_bounds__(512, 4) void conv3x3_relu_k(
    const float* __restrict__ in, const float* __restrict__ wt,
    const float* __restrict__ bias, float* __restrict__ out)
{
  const int cot = blockIdx.x;      // 8 co-tiles of 64
  const int hq  = blockIdx.y;      // 16 row-quads
  const int b   = blockIdx.z;      // image
  const int tid = threadIdx.x;     // 0..511
  const int row = tid >> 7;        // 0..3
  const int t7  = tid & 127;
  const int cog = t7 >> 3;         // 0..15 (4 co each)
  const int pxg = t7 & 7;          // 0..7  (8 px each)
  const int h   = hq * 4 + row;

  __shared__ __align__(16) float s_in[16][6][68];      // [ci][r -1..+4][col+1]
  __shared__ __align__(16) float sA2[16][4][16][4];    // [ci][j][cog][tap0-3]
  __shared__ __align__(16) float sB2[16][4][16][4];    // [ci][j][cog][tap4-7]
  __shared__ float s8[16][64];                         // [ci][co] tap 8

  float accT[8][4], accB[8][4];
  #pragma unroll
  for (int i = 0; i < 8; ++i)
    #pragma unroll
    for (int j = 0; j < 4; ++j) { accT[i][j] = 0.0f; accB[i][j] = 0.0f; }

  for (int ck = 0; ck < 32; ++ck) {
    const int ci0 = ck * 16;
    for (int e = tid; e < 16 * 6 * 66; e += 512) {
      int ci = e / 396, rem = e % 396, r = rem / 66, c = rem % 66;
      int gh = hq * 4 + r - 1, gw = c - 1;
      float v = 0.f;
      if ((unsigned)gh < 64u && (unsigned)gw < 64u)
        v = in[(((size_t)b * 512 + (ci0 + ci)) * 64 + gh) * 64 + gw];
      s_in[ci][r][c] = v;
    }
    for (int e = tid; e < 4096; e += 512) {      // taps 0..3
      int t = e & 3, cg = (e >> 2) & 15, j = (e >> 6) & 3, ci = e >> 8;
      int co = cg * 4 + j;
      sA2[ci][j][cg][t] = wt[(((size_t)(cot * 64 + co)) * 512 + (ci0 + ci)) * 9 + t];
    }
    for (int e = tid; e < 4096; e += 512) {      // taps 4..7
      int t = e & 3, cg = (e >> 2) & 15, j = (e >> 6) & 3, ci = e >> 8;
      int co = cg * 4 + j;
      sB2[ci][j][cg][t] = wt[(((size_t)(cot * 64 + co)) * 512 + (ci0 + ci)) * 9 + 4 + t];
    }
    for (int e = tid; e < 1024; e += 512) {      // tap 8
      int co = e & 63, ci = e >> 6;
      s8[ci][co] = wt[(((size_t)(cot * 64 + co)) * 512 + (ci0 + ci)) * 9 + 8];
    }
    __syncthreads();

    #pragma unroll 1
    for (int kk = 0; kk < 16; ++kk) {
      const int kbase = ck * 144 + kk * 9;
      const int rm = kbase % 384;
      // fold BEFORE element with flat k == 384*m (identical to r10-r13 semantics)
      const int tf = (rm == 0) ? (kbase ? 0 : -1) : ((384 - rm) < 9 ? (384 - rm) : -1);

      float w[4][9];
      #pragma unroll
      for (int j = 0; j < 4; ++j) {
        float4 va = *reinterpret_cast<const float4*>(&sA2[kk][j][cog][0]);
        float4 vb = *reinterpret_cast<const float4*>(&sB2[kk][j][cog][0]);
        w[j][0] = va.x; w[j][1] = va.y; w[j][2] = va.z; w[j][3] = va.w;
        w[j][4] = vb.x; w[j][5] = vb.y; w[j][6] = vb.z; w[j][7] = vb.w;
        w[j][8] = s8[kk][cog * 4 + j];
      }

      if (tf < 0) {
        // FAST PATH (500/512): no fold in this kk — pure fma chain, no guards
        #pragma unroll
        for (int tr = 0; tr < 3; ++tr) {
          float ar[10];
          float4 a0 = *reinterpret_cast<const float4*>(&s_in[kk][row + tr][pxg * 8]);
          float4 a1 = *reinterpret_cast<const float4*>(&s_in[kk][row + tr][pxg * 8 + 4]);
          float2 a2 = *reinterpret_cast<const float2*>(&s_in[kk][row + tr][pxg * 8 + 8]);
          ar[0] = a0.x; ar[1] = a0.y; ar[2] = a0.z; ar[3] = a0.w;
          ar[4] = a1.x; ar[5] = a1.y; ar[6] = a1.z; ar[7] = a1.w;
          ar[8] = a2.x; ar[9] = a2.y;
          #pragma unroll
          for (int tc = 0; tc < 3; ++tc) {
            const int t = tr * 3 + tc;
            #pragma unroll
            for (int i = 0; i < 8; ++i) {
              float av = ar[i + tc];
              accB[i][0] = fmaf(av, w[0][t], accB[i][0]);
              accB[i][1] = fmaf(av, w[1][t], accB[i][1]);
              accB[i][2] = fmaf(av, w[2][t], accB[i][2]);
              accB[i][3] = fmaf(av, w[3][t], accB[i][3]);
            }
          }
        }
      } else {
        // SLOW PATH (12/512): fold at tap tf (identical arithmetic to r13)
        #pragma unroll
        for (int tr = 0; tr < 3; ++tr) {
          float ar[10];
          float4 a0 = *reinterpret_cast<const float4*>(&s_in[kk][row + tr][pxg * 8]);
          float4 a1 = *reinterpret_cast<const float4*>(&s_in[kk][row + tr][pxg * 8 + 4]);
          float2 a2 = *reinterpret_cast<const float2*>(&s_in[kk][row + tr][pxg * 8 + 8]);
          ar[0] = a0.x; ar[1] = a0.y; ar[2] = a0.z; ar[3] = a0.w;
          ar[4] = a1.x; ar[5] = a1.y; ar[6] = a1.z; ar[7] = a1.w;
          ar[8] = a2.x; ar[9] = a2.y;
          #pragma unroll
          for (int tc = 0; tc < 3; ++tc) {
            const int t = tr * 3 + tc;
            if (t == tf) {
              #pragma unroll
              for (int i = 0; i < 8; ++i)
                #pragma unroll
                for (int j = 0; j < 4; ++j) {
                  accT[i][j] = __fadd_rn(accT[i][j], accB[i][j]);
                  accB[i][j] = 0.0f;
                }
            }
            #pragma unroll
            for (int i = 0; i < 8; ++i) {
              float av = ar[i + tc];
              accB[i][0] = fmaf(av, w[0][t], accB[i][0]);
              accB[i][1] = fmaf(av, w[1][t], accB[i][1]);
              accB[i][2] = fmaf(av, w[2][t], accB[i][2]);
              accB[i][3] = fmaf(av, w[3][t], accB[i][3]);
            }
          }
        }
      }
    }
    __syncthreads();
  }

  #pragma unroll
  for (int j = 0; j < 4; ++j) {
    int co = cot * 64 + cog * 4 + j;
    float bv = bias[co];
    float y[8];
    #pragma unroll
    for (int i = 0; i < 8; ++i) {
      float tot = __fadd_rn(accT[i][j], accB[i][j]);
      y[i] = fmaxf(__fadd_rn(tot, bv), 0.0f);
    }
    float4 o0 = { y[0], y[1], y[2], y[3] };
    float4 o1 = { y[4], y[5], y[6], y[7] };
    size_t base = (((size_t)b * 512 + co) * 64 + h) * 64 + pxg * 8;
    *reinterpret_cast<float4*>(&out[base])     = o0;
    *reinterpret_cast<float4*>(&out[base + 4]) = o1;
  }
}

// ---------------- K2: 1x1 heads; fp32 BLAS blocking k=512 -> 384+128 (bit-exact, unchanged) ----------------
__global__ __launch_bounds__(256) void heads_k(
    const float* __restrict__ x, const float* __restrict__ wcls,
    const float* __restrict__ bcls, const float* __restrict__ wbox,
    const float* __restrict__ bbox, float* __restrict__ heads)
{
  const int pg = blockIdx.x & 63, b = blockIdx.x >> 6;
  const int tid = threadIdx.x;
  const int lane = tid & 63, grp = tid >> 6;
  const int pos = pg * 64 + lane;

  __shared__ float s_w[54][128];

  float accT[14], accB[14];
  #pragma unroll
  for (int k = 0; k < 14; ++k) { accT[k] = 0.0f; accB[k] = 0.0f; }

  for (int cc = 0; cc < 4; ++cc) {
    for (int e = tid; e < 54 * 128; e += 256) {
      int o = e >> 7, c = e & 127;
      s_w[o][c] = (o < 18) ? wcls[o * 512 + cc * 128 + c]
                           : wbox[(o - 18) * 512 + cc * 128 + c];
    }
    __syncthreads();
    if (cc == 3) {
      #pragma unroll
      for (int k = 0; k < 14; ++k) { accT[k] = __fadd_rn(accT[k], accB[k]); accB[k] = 0.0f; }
    }
    for (int c = 0; c < 128; ++c) {
      float xv = x[((size_t)b * 512 + cc * 128 + c) * 4096 + pos];
      #pragma unroll
      for (int k = 0; k < 14; ++k) {
        int o = grp + 4 * k;
        if (o < 54) accB[k] = fmaf(xv, s_w[o][c], accB[k]);
      }
    }
    __syncthreads();
  }

  #pragma unroll
  for (int k = 0; k < 14; ++k) {
    int o = grp + 4 * k;
    if (o < 54) {
      float bv = (o < 18) ? bcls[o] : bbox[o - 18];
      float tot = __fadd_rn(accT[k], accB[k]);
      heads[((size_t)b * 54 + o) * 4096 + pos] = __fadd_rn(tot, bv);
    }
  }
}

// ---------------- K3: decode in exact fp32 (bit-exact, unchanged) ----------------
__global__ void decode_k(const float* __restrict__ heads,
                         const float* __restrict__ iminfo,
                         AnchorArgF A,
                         float* __restrict__ prob,
                         float* __restrict__ boxes)
{
  #pragma clang fp contract(off)
  int r = blockIdx.x * blockDim.x + threadIdx.x;
  if (r >= 8 * 36864) return;
  int b = r / 36864, t = r % 36864;
  int pos = t / 9, a = t % 9;
  int hh = pos >> 6, ww = pos & 63;
  float sx = (float)ww * 16.0f, sy = (float)hh * 16.0f;
  float ax1 = A.a[a][0] + sx, ay1 = A.a[a][1] + sy;
  float ax2 = A.a[a][2] + sx, ay2 = A.a[a][3] + sy;

  const float* hb = heads + (size_t)b * 54 * 4096;
  float bg = hb[(size_t)a * 4096 + pos];
  float fg = hb[(size_t)(9 + a) * 4096 + pos];
  float d0 = hb[(size_t)(18 + 4 * a + 0) * 4096 + pos];
  float d1 = hb[(size_t)(18 + 4 * a + 1) * 4096 + pos];
  float d2 = hb[(size_t)(18 + 4 * a + 2) * 4096 + pos];
  float d3 = hb[(size_t)(18 + 4 * a + 3) * 4096 + pos];

  float s32 = __fsub_rn(fg, bg);
  float e32 = (float)exp(-(double)s32);
  float p = __fdiv_rn(1.0f, __fadd_rn(1.0f, e32));

  float w  = (ax2 - ax1) + 1.0f;
  float hgt= (ay2 - ay1) + 1.0f;
  float cx = ax1 + 0.5f * w;
  float cy = ay1 + 0.5f * hgt;
  float pcx = d0 * w + cx;
  float pcy = d1 * hgt + cy;
  float pw = (float)exp((double)d2) * w;
  float ph = (float)exp((double)d3) * hgt;
  float x1 = pcx - 0.5f * pw;
  float y1 = pcy - 0.5f * ph;
  float x2 = pcx + 0.5f * pw;
  float y2 = pcy + 0.5f * ph;

  float imh1 = iminfo[b * 3 + 0] - 1.0f;
  float imw1 = iminfo[b * 3 + 1] - 1.0f;
  float sc   = iminfo[b * 3 + 2];
  x1 = fminf(fmaxf(x1, 0.0f), imw1);
  y1 = fminf(fmaxf(y1, 0.0f), imh1);
  x2 = fminf(fmaxf(x2, 0.0f), imw1);
  y2 = fminf(fmaxf(y2, 0.0f), imh1);

  float ws  = (x2 - x1) + 1.0f;
  float hs2 = (y2 - y1) + 1.0f;
  float ms  = 16.0f * sc;
  if (!(ws >= ms && hs2 >= ms)) p = -1e10f;

  prob[r] = p;
  float* bp = boxes + (size_t)r * 4;
  bp[0] = x1; bp[1] = y1; bp[2] = x2; bp[3] = y2;
}

// ---------------- K4: exact top-6000 sorted (radix-select composite u64 + LDS bitonic) ----------------
__device__ inline unsigned key32_of(float f) {
  unsigned u = __float_as_uint(f);
  return (u & 0x80000000u) ? ~u : (u | 0x80000000u);
}
__device__ inline unsigned long long mk_key(float p, unsigned i) {
  return ((unsigned long long)key32_of(p) << 32) | (unsigned long long)(0xFFFFFFFFu - i);
}

__global__ __launch_bounds__(1024) void topk_k(
    const float* __restrict__ prob, const float* __restrict__ boxes,
    float* __restrict__ tsc, float* __restrict__ tbox)
{
  const int b = blockIdx.x, tid = threadIdx.x;
  const float* pb = prob + (size_t)b * 36864;

  __shared__ unsigned hist[256];
  __shared__ int sk;
  __shared__ unsigned long long spre;
  __shared__ unsigned scnt;
  __shared__ unsigned long long keys[8192];

  if (tid == 0) { sk = 6000; spre = 0ULL; scnt = 0u; }
  __syncthreads();

  for (int byte = 7; byte >= 0; --byte) {
    if (tid < 256) hist[tid] = 0u;
    __syncthreads();
    unsigned long long pre = spre;
    for (int i = tid; i < 36864; i += 1024) {
      unsigned long long k = mk_key(pb[i], (unsigned)i);
      bool match = (byte == 7) || (((k ^ pre) >> ((byte + 1) * 8)) == 0ULL);
      if (match) atomicAdd(&hist[(unsigned)((k >> (byte * 8)) & 0xFF)], 1u);
    }
    __syncthreads();
    if (tid == 0) {
      int k = sk;
      unsigned cum = 0;
      for (int v = 255; v >= 0; --v) {
        unsigned c = hist[v];
        if (cum + c >= (unsigned)k) {
          spre = spre | ((unsigned long long)(unsigned)v << (byte * 8));
          sk = k - (int)cum;
          break;
        }
        cum += c;
      }
    }
    __syncthreads();
  }

  const unsigned long long T = spre;
  for (int i = tid; i < 36864; i += 1024) {
    unsigned long long k = mk_key(pb[i], (unsigned)i);
    if (k >= T) keys[atomicAdd(&scnt, 1u)] = k;
  }
  __syncthreads();
  const int n = (int)scnt;   // == 6000
  for (int i = n + tid; i < 8192; i += 1024) keys[i] = 0ULL;
  __syncthreads();

  for (unsigned k2 = 2; k2 <= 8192u; k2 <<= 1) {
    for (unsigned j = k2 >> 1; j >= 1; j >>= 1) {
      for (unsigned i = tid; i < 8192u; i += 1024) {
        unsigned ixj = i ^ j;
        if (ixj > i) {
          unsigned long long a = keys[i], c = keys[ixj];
          bool descBlock = ((i & k2) == 0);
          if (descBlock ? (a < c) : (a > c)) { keys[i] = c; keys[ixj] = a; }
        }
      }
      __syncthreads();
    }
  }

  for (int s = tid; s < 6000; s += 1024) {
    unsigned long long v = keys[s];
    unsigned idx = 0xFFFFFFFFu - (unsigned)(v & 0xFFFFFFFFu);
    tsc[(size_t)b * 6000 + s] = pb[idx];
    float4 bx = *reinterpret_cast<const float4*>(&boxes[((size_t)b * 36864 + idx) * 4]);
    *reinterpret_cast<float4*>(&tbox[((size_t)b * 6000 + s) * 4]) = bx;
  }
}

// ---------------- K5a: pairwise suppression masks (exact f32 IoU>0.7f, same op order as r13) ----------------
__global__ __launch_bounds__(256) void nmsmask_k(
    const float* __restrict__ tbox, unsigned long long* __restrict__ mask)
{
  #pragma clang fp contract(off)
  const int b = blockIdx.y;
  const int wv = threadIdx.x >> 6, lane = threadIdx.x & 63;
  const int i = blockIdx.x * 4 + wv;          // selected-box row, 0..5999
  const float* tb = tbox + (size_t)b * 6000 * 4;

  float4 bi = *reinterpret_cast<const float4*>(&tb[(size_t)i * 4]);
  float x1 = bi.x, y1 = bi.y, x2 = bi.z, y2 = bi.w;
  float area1 = ((x2 - x1) + 1.0f) * ((y2 - y1) + 1.0f);

  unsigned long long* mrow = mask + ((size_t)b * 6000 + i) * 96;
  for (int w = 0; w < 94; ++w) {
    int j = w * 64 + lane;
    bool pred = false;
    if (j < 6000) {
      float4 bj = *reinterpret_cast<const float4*>(&tb[(size_t)j * 4]);
      float c1 = bj.x, c2 = bj.y, c3 = bj.z, c4 = bj.w;
      float ai = ((c3 - c1) + 1.0f) * ((c4 - c2) + 1.0f);
      float iw = (fminf(x2, c3) - fmaxf(x1, c1)) + 1.0f; iw = fmaxf(iw, 0.0f);
      float ih = (fminf(y2, c4) - fmaxf(y1, c2)) + 1.0f; ih = fmaxf(ih, 0.0f);
      float inter = iw * ih;
      float iou = __fdiv_rn(inter, (area1 + ai) - inter);
      pred = (iou > 0.7f);
    }
    unsigned long long m = __ballot(pred);
    if (lane == 0) mrow[w] = m;
  }
}

// ---------------- K5b: 1-wave serial scan (== sorted-cursor greedy NMS, r13-verified semantics) ----------------
__global__ __launch_bounds__(64) void nmsscan_k(
    const float* __restrict__ tsc, const float* __restrict__ tbox,
    const unsigned long long* __restrict__ mask, float* __restrict__ out)
{
  const int b = blockIdx.x, lane = threadIdx.x;

  __shared__ unsigned long long supp[94];
  __shared__ int s_sel;

  // init suppressed bits: filtered (score <= f32(NEG)*0.5) or j >= 6000
  for (int w = 0; w < 94; ++w) {
    int j = w * 64 + lane;
    bool alive = (j < 6000) && (tsc[(size_t)b * 6000 + j] > -4999999488.0f);
    unsigned long long m = __ballot(!alive);
    if (lane == 0) supp[w] = m;
  }
  __syncthreads();

  int cur = 0;   // meaningful on lane 0 only; selection index is monotone
  for (int r = 0; r < 300; ++r) {
    if (lane == 0) {
      int w = cur >> 6;
      unsigned long long avail = (w < 94) ? (~supp[w] & (~0ULL << (cur & 63))) : 0ULL;
      while (w < 94 && avail == 0ULL) {
        ++w;
        avail = (w < 94) ? ~supp[w] : 0ULL;
      }
      int sel = (w < 94) ? (w * 64 + (int)__builtin_ctzll(avail)) : 6000;
      cur = sel;
      s_sel = sel;
      float* o = out + ((size_t)b * 300 + r) * 5;
      o[0] = (float)b;
      if (sel < 6000) {
        const float* bp = &tbox[((size_t)b * 6000 + sel) * 4];
        o[1] = bp[0]; o[2] = bp[1]; o[3] = bp[2]; o[4] = bp[3];
      } else {
        o[1] = 0.f; o[2] = 0.f; o[3] = 0.f; o[4] = 0.f;
      }
    }
    __syncthreads();
    int j = s_sel;
    if (j < 6000) {
      const unsigned long long* mrow = mask + ((size_t)b * 6000 + j) * 96;
      // OR mask row into suppressed (94 words; lanes cover w and w+64)
      if (lane < 94) supp[lane] |= mrow[lane];
      int w2 = lane + 64;
      if (w2 < 94) supp[w2] |= mrow[w2];
    }
    __syncthreads();
  }
}

extern "C" void kernel_launch(void* const* d_in, const int* in_sizes, int n_in,
                              void* d_out, int out_size, void* d_ws, size_t ws_size,
                              hipStream_t stream) {
  int ib=0, ii=1, iwp=3, ibp=4, iwc=5, ibc=6, iwb=7, ibb=8;
  for (int i = 0; i < n_in; ++i) {
    switch (in_sizes[i]) {
      case 8*512*64*64: ib = i; break;
      case 24:          ii = i; break;
      case 512*512*9:   iwp = i; break;
      case 512:         ibp = i; break;
      case 18*512:      iwc = i; break;
      case 18:          ibc = i; break;
      case 36*512:      iwb = i; break;
      case 36:          ibb = i; break;
      default: break;
    }
  }
  const float* base_feat = (const float*)d_in[ib];
  const float* im_info   = (const float*)d_in[ii];
  const float* w_pre = (const float*)d_in[iwp];
  const float* b_pre = (const float*)d_in[ibp];
  const float* w_cls = (const float*)d_in[iwc];
  const float* b_cls = (const float*)d_in[ibc];
  const float* w_box = (const float*)d_in[iwb];
  const float* b_box = (const float*)d_in[ibb];
  float* out = (float*)d_out;

  char* p = (char*)d_ws;
  float* x      = (float*)p; p += (size_t)8 * 512 * 4096 * 4;    // 64 MiB; dead after heads_k
  float* heads  = (float*)p; p += (size_t)8 * 54 * 4096 * 4;
  float* prob   = (float*)p; p += (size_t)8 * 36864 * 4;
  float* boxes  = (float*)p; p += (size_t)8 * 36864 * 4 * 4;
  float* tsc    = (float*)p; p += (size_t)8 * 6000 * 4;
  float* tbox   = (float*)p; p += (size_t)8 * 6000 * 4 * 4;
  unsigned long long* mask = (unsigned long long*)x;             // reuse x: 8*6000*96*8 = 36.9 MB < 64 MB

  AnchorArgF A;
  {
    const double scales[3] = {8.0, 16.0, 32.0};
    const double ratios[3] = {0.5, 1.0, 2.0};
    const double w = 16.0, h = 16.0, xc = 7.5, yc = 7.5;
    for (int ri = 0; ri < 3; ++ri) {
      double ws_ = nearbyint(sqrt(w * h / ratios[ri]));
      double hs_ = nearbyint(ws_ * ratios[ri]);
      double x1 = xc - 0.5 * (ws_ - 1), y1 = yc - 0.5 * (hs_ - 1);
      double x2 = xc + 0.5 * (ws_ - 1), y2 = yc + 0.5 * (hs_ - 1);
      double w2 = x2 - x1 + 1, h2 = y2 - y1 + 1;
      double xc2 = x1 + 0.5 * (w2 - 1), yc2 = y1 + 0.5 * (h2 - 1);
      for (int si = 0; si < 3; ++si) {
        double wss = w2 * scales[si], hss = h2 * scales[si];
        A.a[ri * 3 + si][0] = (float)(xc2 - 0.5 * (wss - 1));
        A.a[ri * 3 + si][1] = (float)(yc2 - 0.5 * (hss - 1));
        A.a[ri * 3 + si][2] = (float)(xc2 + 0.5 * (wss - 1));
        A.a[ri * 3 + si][3] = (float)(yc2 + 0.5 * (hss - 1));
      }
    }
  }

  conv3x3_relu_k<<<dim3(8, 16, 8), 512, 0, stream>>>(base_feat, w_pre, b_pre, x);
  heads_k<<<512, 256, 0, stream>>>(x, w_cls, b_cls, w_box, b_box, heads);
  decode_k<<<(8 * 36864 + 255) / 256, 256, 0, stream>>>(heads, im_info, A, prob, boxes);
  topk_k<<<8, 1024, 0, stream>>>(prob, boxes, tsc, tbox);
  nmsmask_k<<<dim3(1500, 8), 256, 0, stream>>>(tbox, mask);
  nmsscan_k<<<8, 64, 0, stream>>>(tsc, tbox, mask, out);
}

// Round 15
// 3106.242 us; speedup vs baseline: 6.1200x; 6.1200x over previous
//
#include <hip/hip_runtime.h>
#include <math.h>
#include <cmath>

struct AnchorArgF { float a[9][4]; };

// ---------------- K1: conv 3x3, 512->512, pad 1; fp32, BLAS kc=384 blocking (BIT-EXACT chain):
// flat k=(ci,kh,kw) ascending; per-output fma chain per 384-block, rounded fold-adds.
// v6 = r13 structure (single body, no duplication) + fold guards only at taps {0,3,6}
// (the only possible fold positions since 384m mod 9 cycles 0,6,3). ----------------
__global__ __launch_bounds__(512, 4) void conv3x3_relu_k(
    const float* __restrict__ in, const float* __restrict__ wt,
    const float* __restrict__ bias, float* __restrict__ out)
{
  const int cot = blockIdx.x;      // 8 co-tiles of 64
  const int hq  = blockIdx.y;      // 16 row-quads
  const int b   = blockIdx.z;      // image
  const int tid = threadIdx.x;     // 0..511
  const int row = tid >> 7;        // 0..3
  const int t7  = tid & 127;
  const int cog = t7 >> 3;         // 0..15 (4 co each)
  const int pxg = t7 & 7;          // 0..7  (8 px each)
  const int h   = hq * 4 + row;

  __shared__ __align__(16) float s_in[16][6][68];      // [ci][r -1..+4][col+1]
  __shared__ __align__(16) float sA2[16][4][16][4];    // [ci][j][cog][tap0-3]
  __shared__ __align__(16) float sB2[16][4][16][4];    // [ci][j][cog][tap4-7]
  __shared__ float s8[16][64];                         // [ci][co] tap 8

  float accT[8][4], accB[8][4];
  #pragma unroll
  for (int i = 0; i < 8; ++i)
    #pragma unroll
    for (int j = 0; j < 4; ++j) { accT[i][j] = 0.0f; accB[i][j] = 0.0f; }

  for (int ck = 0; ck < 32; ++ck) {
    const int ci0 = ck * 16;
    for (int e = tid; e < 16 * 6 * 66; e += 512) {
      int ci = e / 396, rem = e % 396, r = rem / 66, c = rem % 66;
      int gh = hq * 4 + r - 1, gw = c - 1;
      float v = 0.f;
      if ((unsigned)gh < 64u && (unsigned)gw < 64u)
        v = in[(((size_t)b * 512 + (ci0 + ci)) * 64 + gh) * 64 + gw];
      s_in[ci][r][c] = v;
    }
    for (int e = tid; e < 4096; e += 512) {      // taps 0..3
      int t = e & 3, cg = (e >> 2) & 15, j = (e >> 6) & 3, ci = e >> 8;
      int co = cg * 4 + j;
      sA2[ci][j][cg][t] = wt[(((size_t)(cot * 64 + co)) * 512 + (ci0 + ci)) * 9 + t];
    }
    for (int e = tid; e < 4096; e += 512) {      // taps 4..7
      int t = e & 3, cg = (e >> 2) & 15, j = (e >> 6) & 3, ci = e >> 8;
      int co = cg * 4 + j;
      sB2[ci][j][cg][t] = wt[(((size_t)(cot * 64 + co)) * 512 + (ci0 + ci)) * 9 + 4 + t];
    }
    for (int e = tid; e < 1024; e += 512) {      // tap 8
      int co = e & 63, ci = e >> 6;
      s8[ci][co] = wt[(((size_t)(cot * 64 + co)) * 512 + (ci0 + ci)) * 9 + 8];
    }
    __syncthreads();

    #pragma unroll 1
    for (int kk = 0; kk < 16; ++kk) {
      const int kbase = ck * 144 + kk * 9;
      const int rm = kbase % 384;
      // fold BEFORE element with flat k == 384*m (identical to r10-r13 semantics).
      // tf can only be -1, 0, 3, or 6: 384m mod 9 cycles {0,6,3}.
      const int tf = (rm == 0) ? (kbase ? 0 : -1) : ((384 - rm) < 9 ? (384 - rm) : -1);
      const bool f0 = (tf == 0), f3 = (tf == 3), f6 = (tf == 6);

      float w[4][9];
      #pragma unroll
      for (int j = 0; j < 4; ++j) {
        float4 va = *reinterpret_cast<const float4*>(&sA2[kk][j][cog][0]);
        float4 vb = *reinterpret_cast<const float4*>(&sB2[kk][j][cog][0]);
        w[j][0] = va.x; w[j][1] = va.y; w[j][2] = va.z; w[j][3] = va.w;
        w[j][4] = vb.x; w[j][5] = vb.y; w[j][6] = vb.z; w[j][7] = vb.w;
        w[j][8] = s8[kk][cog * 4 + j];
      }
      #pragma unroll
      for (int tr = 0; tr < 3; ++tr) {
        float ar[10];
        float4 a0 = *reinterpret_cast<const float4*>(&s_in[kk][row + tr][pxg * 8]);
        float4 a1 = *reinterpret_cast<const float4*>(&s_in[kk][row + tr][pxg * 8 + 4]);
        float2 a2 = *reinterpret_cast<const float2*>(&s_in[kk][row + tr][pxg * 8 + 8]);
        ar[0] = a0.x; ar[1] = a0.y; ar[2] = a0.z; ar[3] = a0.w;
        ar[4] = a1.x; ar[5] = a1.y; ar[6] = a1.z; ar[7] = a1.w;
        ar[8] = a2.x; ar[9] = a2.y;
        #pragma unroll
        for (int tc = 0; tc < 3; ++tc) {
          const int t = tr * 3 + tc;
          // guard exists only at the 3 possible fold taps (compile-time pruned elsewhere)
          const bool doFold = (t == 0) ? f0 : ((t == 3) ? f3 : ((t == 6) ? f6 : false));
          if (doFold) {
            #pragma unroll
            for (int i = 0; i < 8; ++i)
              #pragma unroll
              for (int j = 0; j < 4; ++j) {
                accT[i][j] = __fadd_rn(accT[i][j], accB[i][j]);
                accB[i][j] = 0.0f;
              }
          }
          #pragma unroll
          for (int i = 0; i < 8; ++i) {
            float av = ar[i + tc];
            accB[i][0] = fmaf(av, w[0][t], accB[i][0]);
            accB[i][1] = fmaf(av, w[1][t], accB[i][1]);
            accB[i][2] = fmaf(av, w[2][t], accB[i][2]);
            accB[i][3] = fmaf(av, w[3][t], accB[i][3]);
          }
        }
      }
    }
    __syncthreads();
  }

  #pragma unroll
  for (int j = 0; j < 4; ++j) {
    int co = cot * 64 + cog * 4 + j;
    float bv = bias[co];
    float y[8];
    #pragma unroll
    for (int i = 0; i < 8; ++i) {
      float tot = __fadd_rn(accT[i][j], accB[i][j]);
      y[i] = fmaxf(__fadd_rn(tot, bv), 0.0f);
    }
    float4 o0 = { y[0], y[1], y[2], y[3] };
    float4 o1 = { y[4], y[5], y[6], y[7] };
    size_t base = (((size_t)b * 512 + co) * 64 + h) * 64 + pxg * 8;
    *reinterpret_cast<float4*>(&out[base])     = o0;
    *reinterpret_cast<float4*>(&out[base + 4]) = o1;
  }
}

// ---------------- K2: 1x1 heads; fp32 BLAS blocking k=512 -> 384+128 (bit-exact, unchanged) ----------------
__global__ __launch_bounds__(256) void heads_k(
    const float* __restrict__ x, const float* __restrict__ wcls,
    const float* __restrict__ bcls, const float* __restrict__ wbox,
    const float* __restrict__ bbox, float* __restrict__ heads)
{
  const int pg = blockIdx.x & 63, b = blockIdx.x >> 6;
  const int tid = threadIdx.x;
  const int lane = tid & 63, grp = tid >> 6;
  const int pos = pg * 64 + lane;

  __shared__ float s_w[54][128];

  float accT[14], accB[14];
  #pragma unroll
  for (int k = 0; k < 14; ++k) { accT[k] = 0.0f; accB[k] = 0.0f; }

  for (int cc = 0; cc < 4; ++cc) {
    for (int e = tid; e < 54 * 128; e += 256) {
      int o = e >> 7, c = e & 127;
      s_w[o][c] = (o < 18) ? wcls[o * 512 + cc * 128 + c]
                           : wbox[(o - 18) * 512 + cc * 128 + c];
    }
    __syncthreads();
    if (cc == 3) {
      #pragma unroll
      for (int k = 0; k < 14; ++k) { accT[k] = __fadd_rn(accT[k], accB[k]); accB[k] = 0.0f; }
    }
    for (int c = 0; c < 128; ++c) {
      float xv = x[((size_t)b * 512 + cc * 128 + c) * 4096 + pos];
      #pragma unroll
      for (int k = 0; k < 14; ++k) {
        int o = grp + 4 * k;
        if (o < 54) accB[k] = fmaf(xv, s_w[o][c], accB[k]);
      }
    }
    __syncthreads();
  }

  #pragma unroll
  for (int k = 0; k < 14; ++k) {
    int o = grp + 4 * k;
    if (o < 54) {
      float bv = (o < 18) ? bcls[o] : bbox[o - 18];
      float tot = __fadd_rn(accT[k], accB[k]);
      heads[((size_t)b * 54 + o) * 4096 + pos] = __fadd_rn(tot, bv);
    }
  }
}

// ---------------- K3: decode in exact fp32 (bit-exact, unchanged) ----------------
__global__ void decode_k(const float* __restrict__ heads,
                         const float* __restrict__ iminfo,
                         AnchorArgF A,
                         float* __restrict__ prob,
                         float* __restrict__ boxes)
{
  #pragma clang fp contract(off)
  int r = blockIdx.x * blockDim.x + threadIdx.x;
  if (r >= 8 * 36864) return;
  int b = r / 36864, t = r % 36864;
  int pos = t / 9, a = t % 9;
  int hh = pos >> 6, ww = pos & 63;
  float sx = (float)ww * 16.0f, sy = (float)hh * 16.0f;
  float ax1 = A.a[a][0] + sx, ay1 = A.a[a][1] + sy;
  float ax2 = A.a[a][2] + sx, ay2 = A.a[a][3] + sy;

  const float* hb = heads + (size_t)b * 54 * 4096;
  float bg = hb[(size_t)a * 4096 + pos];
  float fg = hb[(size_t)(9 + a) * 4096 + pos];
  float d0 = hb[(size_t)(18 + 4 * a + 0) * 4096 + pos];
  float d1 = hb[(size_t)(18 + 4 * a + 1) * 4096 + pos];
  float d2 = hb[(size_t)(18 + 4 * a + 2) * 4096 + pos];
  float d3 = hb[(size_t)(18 + 4 * a + 3) * 4096 + pos];

  float s32 = __fsub_rn(fg, bg);
  float e32 = (float)exp(-(double)s32);
  float p = __fdiv_rn(1.0f, __fadd_rn(1.0f, e32));

  float w  = (ax2 - ax1) + 1.0f;
  float hgt= (ay2 - ay1) + 1.0f;
  float cx = ax1 + 0.5f * w;
  float cy = ay1 + 0.5f * hgt;
  float pcx = d0 * w + cx;
  float pcy = d1 * hgt + cy;
  float pw = (float)exp((double)d2) * w;
  float ph = (float)exp((double)d3) * hgt;
  float x1 = pcx - 0.5f * pw;
  float y1 = pcy - 0.5f * ph;
  float x2 = pcx + 0.5f * pw;
  float y2 = pcy + 0.5f * ph;

  float imh1 = iminfo[b * 3 + 0] - 1.0f;
  float imw1 = iminfo[b * 3 + 1] - 1.0f;
  float sc   = iminfo[b * 3 + 2];
  x1 = fminf(fmaxf(x1, 0.0f), imw1);
  y1 = fminf(fmaxf(y1, 0.0f), imh1);
  x2 = fminf(fmaxf(x2, 0.0f), imw1);
  y2 = fminf(fmaxf(y2, 0.0f), imh1);

  float ws  = (x2 - x1) + 1.0f;
  float hs2 = (y2 - y1) + 1.0f;
  float ms  = 16.0f * sc;
  if (!(ws >= ms && hs2 >= ms)) p = -1e10f;

  prob[r] = p;
  float* bp = boxes + (size_t)r * 4;
  bp[0] = x1; bp[1] = y1; bp[2] = x2; bp[3] = y2;
}

// ---------------- K4: exact top-6000 sorted (radix-select composite u64 + LDS bitonic) ----------------
__device__ inline unsigned key32_of(float f) {
  unsigned u = __float_as_uint(f);
  return (u & 0x80000000u) ? ~u : (u | 0x80000000u);
}
__device__ inline unsigned long long mk_key(float p, unsigned i) {
  return ((unsigned long long)key32_of(p) << 32) | (unsigned long long)(0xFFFFFFFFu - i);
}

__global__ __launch_bounds__(1024) void topk_k(
    const float* __restrict__ prob, const float* __restrict__ boxes,
    float* __restrict__ tsc, float* __restrict__ tbox)
{
  const int b = blockIdx.x, tid = threadIdx.x;
  const float* pb = prob + (size_t)b * 36864;

  __shared__ unsigned hist[256];
  __shared__ int sk;
  __shared__ unsigned long long spre;
  __shared__ unsigned scnt;
  __shared__ unsigned long long keys[8192];

  if (tid == 0) { sk = 6000; spre = 0ULL; scnt = 0u; }
  __syncthreads();

  for (int byte = 7; byte >= 0; --byte) {
    if (tid < 256) hist[tid] = 0u;
    __syncthreads();
    unsigned long long pre = spre;
    for (int i = tid; i < 36864; i += 1024) {
      unsigned long long k = mk_key(pb[i], (unsigned)i);
      bool match = (byte == 7) || (((k ^ pre) >> ((byte + 1) * 8)) == 0ULL);
      if (match) atomicAdd(&hist[(unsigned)((k >> (byte * 8)) & 0xFF)], 1u);
    }
    __syncthreads();
    if (tid == 0) {
      int k = sk;
      unsigned cum = 0;
      for (int v = 255; v >= 0; --v) {
        unsigned c = hist[v];
        if (cum + c >= (unsigned)k) {
          spre = spre | ((unsigned long long)(unsigned)v << (byte * 8));
          sk = k - (int)cum;
          break;
        }
        cum += c;
      }
    }
    __syncthreads();
  }

  const unsigned long long T = spre;
  for (int i = tid; i < 36864; i += 1024) {
    unsigned long long k = mk_key(pb[i], (unsigned)i);
    if (k >= T) keys[atomicAdd(&scnt, 1u)] = k;
  }
  __syncthreads();
  const int n = (int)scnt;   // == 6000
  for (int i = n + tid; i < 8192; i += 1024) keys[i] = 0ULL;
  __syncthreads();

  for (unsigned k2 = 2; k2 <= 8192u; k2 <<= 1) {
    for (unsigned j = k2 >> 1; j >= 1; j >>= 1) {
      for (unsigned i = tid; i < 8192u; i += 1024) {
        unsigned ixj = i ^ j;
        if (ixj > i) {
          unsigned long long a = keys[i], c = keys[ixj];
          bool descBlock = ((i & k2) == 0);
          if (descBlock ? (a < c) : (a > c)) { keys[i] = c; keys[ixj] = a; }
        }
      }
      __syncthreads();
    }
  }

  for (int s = tid; s < 6000; s += 1024) {
    unsigned long long v = keys[s];
    unsigned idx = 0xFFFFFFFFu - (unsigned)(v & 0xFFFFFFFFu);
    tsc[(size_t)b * 6000 + s] = pb[idx];
    float4 bx = *reinterpret_cast<const float4*>(&boxes[((size_t)b * 36864 + idx) * 4]);
    *reinterpret_cast<float4*>(&tbox[((size_t)b * 6000 + s) * 4]) = bx;
  }
}

// ---------------- K5a: pairwise suppression masks (exact f32 IoU>0.7f) ----------------
__global__ __launch_bounds__(256) void nmsmask_k(
    const float* __restrict__ tbox, unsigned long long* __restrict__ mask)
{
  #pragma clang fp contract(off)
  const int b = blockIdx.y;
  const int wv = threadIdx.x >> 6, lane = threadIdx.x & 63;
  const int i = blockIdx.x * 4 + wv;          // selected-box row, 0..5999
  const float* tb = tbox + (size_t)b * 6000 * 4;

  float4 bi = *reinterpret_cast<const float4*>(&tb[(size_t)i * 4]);
  float x1 = bi.x, y1 = bi.y, x2 = bi.z, y2 = bi.w;
  float area1 = ((x2 - x1) + 1.0f) * ((y2 - y1) + 1.0f);

  unsigned long long* mrow = mask + ((size_t)b * 6000 + i) * 96;
  for (int w = 0; w < 94; ++w) {
    int j = w * 64 + lane;
    bool pred = false;
    if (j < 6000) {
      float4 bj = *reinterpret_cast<const float4*>(&tb[(size_t)j * 4]);
      float c1 = bj.x, c2 = bj.y, c3 = bj.z, c4 = bj.w;
      float ai = ((c3 - c1) + 1.0f) * ((c4 - c2) + 1.0f);
      float iw = (fminf(x2, c3) - fmaxf(x1, c1)) + 1.0f; iw = fmaxf(iw, 0.0f);
      float ih = (fminf(y2, c4) - fmaxf(y1, c2)) + 1.0f; ih = fmaxf(ih, 0.0f);
      float inter = iw * ih;
      float iou = __fdiv_rn(inter, (area1 + ai) - inter);
      pred = (iou > 0.7f);
    }
    unsigned long long m = __ballot(pred);
    if (lane == 0) mrow[w] = m;
  }
}

// ---------------- K5b: 1-wave serial scan (== sorted-cursor greedy NMS) ----------------
__global__ __launch_bounds__(64) void nmsscan_k(
    const float* __restrict__ tsc, const float* __restrict__ tbox,
    const unsigned long long* __restrict__ mask, float* __restrict__ out)
{
  const int b = blockIdx.x, lane = threadIdx.x;

  __shared__ unsigned long long supp[94];
  __shared__ int s_sel;

  for (int w = 0; w < 94; ++w) {
    int j = w * 64 + lane;
    bool alive = (j < 6000) && (tsc[(size_t)b * 6000 + j] > -4999999488.0f);
    unsigned long long m = __ballot(!alive);
    if (lane == 0) supp[w] = m;
  }
  __syncthreads();

  int cur = 0;
  for (int r = 0; r < 300; ++r) {
    if (lane == 0) {
      int w = cur >> 6;
      unsigned long long avail = (w < 94) ? (~supp[w] & (~0ULL << (cur & 63))) : 0ULL;
      while (w < 94 && avail == 0ULL) {
        ++w;
        avail = (w < 94) ? ~supp[w] : 0ULL;
      }
      int sel = (w < 94) ? (w * 64 + (int)__builtin_ctzll(avail)) : 6000;
      cur = sel;
      s_sel = sel;
      float* o = out + ((size_t)b * 300 + r) * 5;
      o[0] = (float)b;
      if (sel < 6000) {
        const float* bp = &tbox[((size_t)b * 6000 + sel) * 4];
        o[1] = bp[0]; o[2] = bp[1]; o[3] = bp[2]; o[4] = bp[3];
      } else {
        o[1] = 0.f; o[2] = 0.f; o[3] = 0.f; o[4] = 0.f;
      }
    }
    __syncthreads();
    int j = s_sel;
    if (j < 6000) {
      const unsigned long long* mrow = mask + ((size_t)b * 6000 + j) * 96;
      if (lane < 94) supp[lane] |= mrow[lane];
      int w2 = lane + 64;
      if (w2 < 94) supp[w2] |= mrow[w2];
    }
    __syncthreads();
  }
}

extern "C" void kernel_launch(void* const* d_in, const int* in_sizes, int n_in,
                              void* d_out, int out_size, void* d_ws, size_t ws_size,
                              hipStream_t stream) {
  int ib=0, ii=1, iwp=3, ibp=4, iwc=5, ibc=6, iwb=7, ibb=8;
  for (int i = 0; i < n_in; ++i) {
    switch (in_sizes[i]) {
      case 8*512*64*64: ib = i; break;
      case 24:          ii = i; break;
      case 512*512*9:   iwp = i; break;
      case 512:         ibp = i; break;
      case 18*512:      iwc = i; break;
      case 18:          ibc = i; break;
      case 36*512:      iwb = i; break;
      case 36:          ibb = i; break;
      default: break;
    }
  }
  const float* base_feat = (const float*)d_in[ib];
  const float* im_info   = (const float*)d_in[ii];
  const float* w_pre = (const float*)d_in[iwp];
  const float* b_pre = (const float*)d_in[ibp];
  const float* w_cls = (const float*)d_in[iwc];
  const float* b_cls = (const float*)d_in[ibc];
  const float* w_box = (const float*)d_in[iwb];
  const float* b_box = (const float*)d_in[ibb];
  float* out = (float*)d_out;

  char* p = (char*)d_ws;
  float* x      = (float*)p; p += (size_t)8 * 512 * 4096 * 4;    // 64 MiB; dead after heads_k
  float* heads  = (float*)p; p += (size_t)8 * 54 * 4096 * 4;
  float* prob   = (float*)p; p += (size_t)8 * 36864 * 4;
  float* boxes  = (float*)p; p += (size_t)8 * 36864 * 4 * 4;
  float* tsc    = (float*)p; p += (size_t)8 * 6000 * 4;
  float* tbox   = (float*)p; p += (size_t)8 * 6000 * 4 * 4;
  unsigned long long* mask = (unsigned long long*)x;             // reuse x: 36.9 MB < 64 MB

  AnchorArgF A;
  {
    const double scales[3] = {8.0, 16.0, 32.0};
    const double ratios[3] = {0.5, 1.0, 2.0};
    const double w = 16.0, h = 16.0, xc = 7.5, yc = 7.5;
    for (int ri = 0; ri < 3; ++ri) {
      double ws_ = nearbyint(sqrt(w * h / ratios[ri]));
      double hs_ = nearbyint(ws_ * ratios[ri]);
      double x1 = xc - 0.5 * (ws_ - 1), y1 = yc - 0.5 * (hs_ - 1);
      double x2 = xc + 0.5 * (ws_ - 1), y2 = yc + 0.5 * (hs_ - 1);
      double w2 = x2 - x1 + 1, h2 = y2 - y1 + 1;
      double xc2 = x1 + 0.5 * (w2 - 1), yc2 = y1 + 0.5 * (h2 - 1);
      for (int si = 0; si < 3; ++si) {
        double wss = w2 * scales[si], hss = h2 * scales[si];
        A.a[ri * 3 + si][0] = (float)(xc2 - 0.5 * (wss - 1));
        A.a[ri * 3 + si][1] = (float)(yc2 - 0.5 * (hss - 1));
        A.a[ri * 3 + si][2] = (float)(xc2 + 0.5 * (wss - 1));
        A.a[ri * 3 + si][3] = (float)(yc2 + 0.5 * (hss - 1));
      }
    }
  }

  conv3x3_relu_k<<<dim3(8, 16, 8), 512, 0, stream>>>(base_feat, w_pre, b_pre, x);
  heads_k<<<512, 256, 0, stream>>>(x, w_cls, b_cls, w_box, b_box, heads);
  decode_k<<<(8 * 36864 + 255) / 256, 256, 0, stream>>>(heads, im_info, A, prob, boxes);
  topk_k<<<8, 1024, 0, stream>>>(prob, boxes, tsc, tbox);
  nmsmask_k<<<dim3(1500, 8), 256, 0, stream>>>(tbox, mask);
  nmsscan_k<<<8, 64, 0, stream>>>(tsc, tbox, mask, out);
}